// Round 1
// baseline (650.165 us; speedup 1.0000x reference)
//
#include <hip/hip_runtime.h>
#include <math.h>

#define N_NODES 100000
#define E_EDGES 1600000
#define IN_F 256
#define OUT_F 128
#define LRELU_ALPHA 0.2f

// ---------------------------------------------------------------------------
// Kernel 1: Wh = h @ W   (fp32 vector GEMM, register-blocked 8 rows/thread)
// block = 128 threads (one per output col), grid = N/8.
// W reads coalesced across the 128 col-threads; h reads are wave-uniform
// (same row for all threads in the block) -> scalar loads + broadcast.
// ---------------------------------------------------------------------------
__global__ __launch_bounds__(OUT_F) void gemm_kernel(
    const float* __restrict__ h, const float* __restrict__ W,
    float* __restrict__ Wh) {
  const int c = threadIdx.x;           // output column 0..127
  const int r0 = blockIdx.x * 8;       // 8 rows per block
  float acc[8] = {0.f, 0.f, 0.f, 0.f, 0.f, 0.f, 0.f, 0.f};
  for (int k = 0; k < IN_F; k += 4) {
    const float w0 = W[(k + 0) * OUT_F + c];
    const float w1 = W[(k + 1) * OUT_F + c];
    const float w2 = W[(k + 2) * OUT_F + c];
    const float w3 = W[(k + 3) * OUT_F + c];
#pragma unroll
    for (int r = 0; r < 8; ++r) {
      const float4 hv = *reinterpret_cast<const float4*>(&h[(r0 + r) * IN_F + k]);
      acc[r] = fmaf(hv.x, w0, acc[r]);
      acc[r] = fmaf(hv.y, w1, acc[r]);
      acc[r] = fmaf(hv.z, w2, acc[r]);
      acc[r] = fmaf(hv.w, w3, acc[r]);
    }
  }
#pragma unroll
  for (int r = 0; r < 8; ++r) Wh[(r0 + r) * OUT_F + c] = acc[r];
}

// ---------------------------------------------------------------------------
// Kernel 2: f1[r] = Wh[r,:] . a_src ; f2[r] = Wh[r,:] . a_dest
// block = 256 threads = 4 waves, one wave per row, float2 per lane.
// ---------------------------------------------------------------------------
__global__ __launch_bounds__(256) void fscore_kernel(
    const float* __restrict__ Wh, const float* __restrict__ a_src,
    const float* __restrict__ a_dst, float* __restrict__ f1,
    float* __restrict__ f2) {
  const int wave = threadIdx.x >> 6;   // 0..3
  const int lane = threadIdx.x & 63;
  const int r = blockIdx.x * 4 + wave;
  const float2 v  = *reinterpret_cast<const float2*>(&Wh[r * OUT_F + lane * 2]);
  const float2 as = *reinterpret_cast<const float2*>(&a_src[lane * 2]);
  const float2 ad = *reinterpret_cast<const float2*>(&a_dst[lane * 2]);
  float p1 = v.x * as.x + v.y * as.y;
  float p2 = v.x * ad.x + v.y * ad.y;
#pragma unroll
  for (int o = 32; o > 0; o >>= 1) {
    p1 += __shfl_xor(p1, o);
    p2 += __shfl_xor(p2, o);
  }
  if (lane == 0) {
    f1[r] = p1;
    f2[r] = p2;
  }
}

// ---------------------------------------------------------------------------
// Kernel 3: row_ptr[i] = lower_bound(row, i)   (row is sorted)
// ---------------------------------------------------------------------------
__global__ void rowptr_kernel(const int* __restrict__ row,
                              int* __restrict__ row_ptr) {
  const int i = blockIdx.x * blockDim.x + threadIdx.x;
  if (i > N_NODES) return;
  int lo = 0, hi = E_EDGES;
  while (lo < hi) {
    const int mid = (lo + hi) >> 1;
    if (row[mid] < i) lo = mid + 1; else hi = mid;
  }
  row_ptr[i] = lo;
}

// ---------------------------------------------------------------------------
// Kernel 4: per-node segment softmax + SpMM + ELU.
// One block (128 threads) per node; thread t owns feature t.
// Pass 1/2: segment max & exp-sum (strided over edges, block reduce).
// Pass 3: chunk edges into LDS (att, col), then coalesced 512B/edge gather
//         of Wh[col] accumulated per-feature.
// ---------------------------------------------------------------------------
__global__ __launch_bounds__(OUT_F) void gat_kernel(
    const float* __restrict__ Wh, const float* __restrict__ f1,
    const float* __restrict__ f2, const int* __restrict__ row_ptr,
    const int* __restrict__ col, float* __restrict__ out) {
  __shared__ float s_red[2];
  __shared__ float s_att[128];
  __shared__ int s_col[128];

  const int i = blockIdx.x;
  const int t = threadIdx.x;
  const int start = row_ptr[i];
  const int end = row_ptr[i + 1];
  const int deg = end - start;
  if (deg == 0) {  // empty segment: segment_sum -> 0, elu(0) = 0
    out[i * OUT_F + t] = 0.f;
    return;
  }
  const float f1i = f1[i];

  // pass 1: segment max of leaky_relu(f1[i] + f2[col])
  float lm = -INFINITY;
  for (int e = start + t; e < end; e += OUT_F) {
    float v = f1i + f2[col[e]];
    v = v > 0.f ? v : LRELU_ALPHA * v;
    lm = fmaxf(lm, v);
  }
#pragma unroll
  for (int o = 32; o > 0; o >>= 1) lm = fmaxf(lm, __shfl_xor(lm, o));
  if ((t & 63) == 0) s_red[t >> 6] = lm;
  __syncthreads();
  const float m = fmaxf(s_red[0], s_red[1]);
  __syncthreads();

  // pass 2: sum of exp(v - m)
  float ls = 0.f;
  for (int e = start + t; e < end; e += OUT_F) {
    float v = f1i + f2[col[e]];
    v = v > 0.f ? v : LRELU_ALPHA * v;
    ls += expf(v - m);
  }
#pragma unroll
  for (int o = 32; o > 0; o >>= 1) ls += __shfl_xor(ls, o);
  if ((t & 63) == 0) s_red[t >> 6] = ls;
  __syncthreads();
  const float inv_denom = 1.f / (s_red[0] + s_red[1]);

  // pass 3: weighted feature accumulation
  float acc = 0.f;
  for (int c0 = start; c0 < end; c0 += 128) {
    __syncthreads();
    const int chunk = min(128, end - c0);
    if (t < chunk) {
      const int cj = col[c0 + t];
      float v = f1i + f2[cj];
      v = v > 0.f ? v : LRELU_ALPHA * v;
      s_att[t] = expf(v - m) * inv_denom;
      s_col[t] = cj;
    }
    __syncthreads();
    for (int j = 0; j < chunk; ++j)
      acc = fmaf(s_att[j], Wh[s_col[j] * OUT_F + t], acc);
  }
  // ELU (alpha = 1)
  out[i * OUT_F + t] = acc > 0.f ? acc : expm1f(acc);
}

// ---------------------------------------------------------------------------
extern "C" void kernel_launch(void* const* d_in, const int* in_sizes, int n_in,
                              void* d_out, int out_size, void* d_ws,
                              size_t ws_size, hipStream_t stream) {
  const float* h     = (const float*)d_in[0];
  const float* W     = (const float*)d_in[1];
  const float* a_src = (const float*)d_in[2];
  const float* a_dst = (const float*)d_in[3];
  const int*   row   = (const int*)d_in[4];
  const int*   col   = (const int*)d_in[5];
  float* out = (float*)d_out;

  char* ws = (char*)d_ws;
  float* Wh      = (float*)(ws);                 // N*128*4 = 51,200,000 B
  float* f1      = (float*)(ws + 51200000);      // N*4     =    400,000 B
  float* f2      = (float*)(ws + 51600000);      // N*4     =    400,000 B
  int*   row_ptr = (int*)  (ws + 52000000);      // (N+1)*4 =    400,004 B

  hipLaunchKernelGGL(gemm_kernel, dim3(N_NODES / 8), dim3(OUT_F), 0, stream,
                     h, W, Wh);
  hipLaunchKernelGGL(fscore_kernel, dim3(N_NODES / 4), dim3(256), 0, stream,
                     Wh, a_src, a_dst, f1, f2);
  hipLaunchKernelGGL(rowptr_kernel, dim3((N_NODES + 256) / 256), dim3(256), 0,
                     stream, row, row_ptr);
  hipLaunchKernelGGL(gat_kernel, dim3(N_NODES), dim3(OUT_F), 0, stream,
                     Wh, f1, f2, row_ptr, col, out);
}

// Round 2
// 380.252 us; speedup vs baseline: 1.7098x; 1.7098x over previous
//
#include <hip/hip_runtime.h>
#include <math.h>

#define N_NODES 100000
#define E_EDGES 1600000
#define IN_F 256
#define OUT_F 128
#define LRELU_ALPHA 0.2f

#define BM 64
#define BN 128
#define BK 32
#define TM 8
#define TN 4

// ---------------------------------------------------------------------------
// Kernel 1: Wh = h @ W  (fp32, LDS-tiled, 8x4 register block per thread)
// + fused epilogue: f1 = Wh . a_src, f2 = Wh . a_dest (block owns full rows).
// 256 threads = (tx 0..31) x (ty 0..7); thread computes rows ty*8..+7,
// cols tx*4..+3. A-tile transposed in LDS so the 8-row fragment is 2 float4
// reads; B-tile rows are float4 reads.
// ---------------------------------------------------------------------------
__global__ __launch_bounds__(256) void gemm_fused(
    const float* __restrict__ h, const float* __restrict__ W,
    const float* __restrict__ a_src, const float* __restrict__ a_dst,
    float* __restrict__ Wh, float* __restrict__ f1, float* __restrict__ f2) {
  __shared__ float As[BK][BM + 4];  // transposed: As[k][m]; +4 keeps float4
                                    // alignment, write conflicts <= 4-way
  __shared__ float Bs[BK][BN];

  const int tid = threadIdx.x;
  const int tx = tid & 31;   // col group
  const int ty = tid >> 5;   // row group
  const int m0 = blockIdx.x * BM;

  // staging coordinates
  const int ar = tid >> 3;         // 0..31 (A row within tile)
  const int ac = (tid & 7) * 4;    // 0..28 (A col, float4)
  const int br = tid >> 5;         // 0..7  (B row within tile)
  const int bc = (tid & 31) * 4;   // 0..124 (B col, float4)

  float acc[TM][TN];
#pragma unroll
  for (int r = 0; r < TM; ++r)
#pragma unroll
    for (int c = 0; c < TN; ++c) acc[r][c] = 0.f;

  for (int k0 = 0; k0 < IN_F; k0 += BK) {
    // global loads for this tile (issued before the barrier for overlap)
    const int ra0 = min(m0 + ar, N_NODES - 1);
    const int ra1 = min(m0 + ar + 32, N_NODES - 1);
    const float4 av0 = *reinterpret_cast<const float4*>(&h[ra0 * IN_F + k0 + ac]);
    const float4 av1 = *reinterpret_cast<const float4*>(&h[ra1 * IN_F + k0 + ac]);
    const float4 bv0 = *reinterpret_cast<const float4*>(&W[(k0 + br) * OUT_F + bc]);
    const float4 bv1 = *reinterpret_cast<const float4*>(&W[(k0 + br + 8) * OUT_F + bc]);
    const float4 bv2 = *reinterpret_cast<const float4*>(&W[(k0 + br + 16) * OUT_F + bc]);
    const float4 bv3 = *reinterpret_cast<const float4*>(&W[(k0 + br + 24) * OUT_F + bc]);

    __syncthreads();  // previous tile's LDS reads done
    As[ac + 0][ar] = av0.x;
    As[ac + 1][ar] = av0.y;
    As[ac + 2][ar] = av0.z;
    As[ac + 3][ar] = av0.w;
    As[ac + 0][ar + 32] = av1.x;
    As[ac + 1][ar + 32] = av1.y;
    As[ac + 2][ar + 32] = av1.z;
    As[ac + 3][ar + 32] = av1.w;
    *reinterpret_cast<float4*>(&Bs[br][bc]) = bv0;
    *reinterpret_cast<float4*>(&Bs[br + 8][bc]) = bv1;
    *reinterpret_cast<float4*>(&Bs[br + 16][bc]) = bv2;
    *reinterpret_cast<float4*>(&Bs[br + 24][bc]) = bv3;
    __syncthreads();

#pragma unroll 8
    for (int k = 0; k < BK; ++k) {
      const float4 b = *reinterpret_cast<const float4*>(&Bs[k][tx * 4]);
      const float4 a0 = *reinterpret_cast<const float4*>(&As[k][ty * 8]);
      const float4 a1 = *reinterpret_cast<const float4*>(&As[k][ty * 8 + 4]);
      const float a[TM] = {a0.x, a0.y, a0.z, a0.w, a1.x, a1.y, a1.z, a1.w};
      const float bb[TN] = {b.x, b.y, b.z, b.w};
#pragma unroll
      for (int r = 0; r < TM; ++r)
#pragma unroll
        for (int c = 0; c < TN; ++c) acc[r][c] = fmaf(a[r], bb[c], acc[r][c]);
    }
  }

  // epilogue: store Wh + fused f1/f2 (reduce over the 32 tx lanes)
  const float4 as4 = *reinterpret_cast<const float4*>(&a_src[tx * 4]);
  const float4 ad4 = *reinterpret_cast<const float4*>(&a_dst[tx * 4]);
#pragma unroll
  for (int r = 0; r < TM; ++r) {
    const int row = m0 + ty * TM + r;
    const bool live = row < N_NODES;
    if (live) {
      float4 o = {acc[r][0], acc[r][1], acc[r][2], acc[r][3]};
      *reinterpret_cast<float4*>(&Wh[row * OUT_F + tx * 4]) = o;
    }
    float p1 = acc[r][0] * as4.x + acc[r][1] * as4.y + acc[r][2] * as4.z +
               acc[r][3] * as4.w;
    float p2 = acc[r][0] * ad4.x + acc[r][1] * ad4.y + acc[r][2] * ad4.z +
               acc[r][3] * ad4.w;
#pragma unroll
    for (int o = 16; o > 0; o >>= 1) {  // reduce within the 32-lane tx half
      p1 += __shfl_xor(p1, o);
      p2 += __shfl_xor(p2, o);
    }
    if (live && tx == 0) {
      f1[row] = p1;
      f2[row] = p2;
    }
  }
}

// ---------------------------------------------------------------------------
// Kernel 2: row_ptr[i] = lower_bound(row, i)   (row is sorted)
// ---------------------------------------------------------------------------
__global__ void rowptr_kernel(const int* __restrict__ row,
                              int* __restrict__ row_ptr) {
  const int i = blockIdx.x * blockDim.x + threadIdx.x;
  if (i > N_NODES) return;
  int lo = 0, hi = E_EDGES;
  while (lo < hi) {
    const int mid = (lo + hi) >> 1;
    if (row[mid] < i) lo = mid + 1; else hi = mid;
  }
  row_ptr[i] = lo;
}

// ---------------------------------------------------------------------------
// Kernel 3: per-node segment softmax + SpMM + ELU.
// One block (128 threads) per node; thread t owns feature t.
// ---------------------------------------------------------------------------
__global__ __launch_bounds__(OUT_F) void gat_kernel(
    const float* __restrict__ Wh, const float* __restrict__ f1,
    const float* __restrict__ f2, const int* __restrict__ row_ptr,
    const int* __restrict__ col, float* __restrict__ out) {
  __shared__ float s_red[2];
  __shared__ float s_att[128];
  __shared__ int s_col[128];

  const int i = blockIdx.x;
  const int t = threadIdx.x;
  const int start = row_ptr[i];
  const int end = row_ptr[i + 1];
  const int deg = end - start;
  if (deg == 0) {  // empty segment: segment_sum -> 0, elu(0) = 0
    out[i * OUT_F + t] = 0.f;
    return;
  }
  const float f1i = f1[i];

  // pass 1: segment max of leaky_relu(f1[i] + f2[col])
  float lm = -INFINITY;
  for (int e = start + t; e < end; e += OUT_F) {
    float v = f1i + f2[col[e]];
    v = v > 0.f ? v : LRELU_ALPHA * v;
    lm = fmaxf(lm, v);
  }
#pragma unroll
  for (int o = 32; o > 0; o >>= 1) lm = fmaxf(lm, __shfl_xor(lm, o));
  if ((t & 63) == 0) s_red[t >> 6] = lm;
  __syncthreads();
  const float m = fmaxf(s_red[0], s_red[1]);
  __syncthreads();

  // pass 2: sum of exp(v - m)
  float ls = 0.f;
  for (int e = start + t; e < end; e += OUT_F) {
    float v = f1i + f2[col[e]];
    v = v > 0.f ? v : LRELU_ALPHA * v;
    ls += expf(v - m);
  }
#pragma unroll
  for (int o = 32; o > 0; o >>= 1) ls += __shfl_xor(ls, o);
  if ((t & 63) == 0) s_red[t >> 6] = ls;
  __syncthreads();
  const float inv_denom = 1.f / (s_red[0] + s_red[1]);

  // pass 3: weighted feature accumulation
  float acc = 0.f;
  for (int c0 = start; c0 < end; c0 += 128) {
    __syncthreads();
    const int chunk = min(128, end - c0);
    if (t < chunk) {
      const int cj = col[c0 + t];
      float v = f1i + f2[cj];
      v = v > 0.f ? v : LRELU_ALPHA * v;
      s_att[t] = expf(v - m) * inv_denom;
      s_col[t] = cj;
    }
    __syncthreads();
    for (int j = 0; j < chunk; ++j)
      acc = fmaf(s_att[j], Wh[s_col[j] * OUT_F + t], acc);
  }
  // ELU (alpha = 1)
  out[i * OUT_F + t] = acc > 0.f ? acc : expm1f(acc);
}

// ---------------------------------------------------------------------------
extern "C" void kernel_launch(void* const* d_in, const int* in_sizes, int n_in,
                              void* d_out, int out_size, void* d_ws,
                              size_t ws_size, hipStream_t stream) {
  const float* h     = (const float*)d_in[0];
  const float* W     = (const float*)d_in[1];
  const float* a_src = (const float*)d_in[2];
  const float* a_dst = (const float*)d_in[3];
  const int*   row   = (const int*)d_in[4];
  const int*   col   = (const int*)d_in[5];
  float* out = (float*)d_out;

  char* ws = (char*)d_ws;
  float* Wh      = (float*)(ws);                 // N*128*4 = 51,200,000 B
  float* f1      = (float*)(ws + 51200000);      // N*4     =    400,000 B
  float* f2      = (float*)(ws + 51600000);      // N*4     =    400,000 B
  int*   row_ptr = (int*)  (ws + 52000000);      // (N+1)*4 =    400,004 B

  const int gemm_grid = (N_NODES + BM - 1) / BM;
  hipLaunchKernelGGL(gemm_fused, dim3(gemm_grid), dim3(256), 0, stream,
                     h, W, a_src, a_dst, Wh, f1, f2);
  hipLaunchKernelGGL(rowptr_kernel, dim3((N_NODES + 256) / 256), dim3(256), 0,
                     stream, row, row_ptr);
  hipLaunchKernelGGL(gat_kernel, dim3(N_NODES), dim3(OUT_F), 0, stream,
                     Wh, f1, f2, row_ptr, col, out);
}

// Round 4
// 276.630 us; speedup vs baseline: 2.3503x; 1.3746x over previous
//
#include <hip/hip_runtime.h>
#include <math.h>

#define N_NODES 100000
#define E_EDGES 1600000
#define IN_F 256
#define OUT_F 128
#define LRELU_ALPHA 0.2f

typedef __attribute__((ext_vector_type(8))) short bf16x8;
typedef __attribute__((ext_vector_type(4))) float f32x4;

__device__ __forceinline__ unsigned short f32_to_bf16(float f) {
  unsigned int u = __float_as_uint(f);
  u = (u + 0x7fffu + ((u >> 16) & 1u)) >> 16;  // round-to-nearest-even
  return (unsigned short)u;
}
__device__ __forceinline__ unsigned int pack_bf16x2(float a, float b) {
  return (unsigned int)f32_to_bf16(a) | ((unsigned int)f32_to_bf16(b) << 16);
}

// ---------------------------------------------------------------------------
// Prep A: row_ptr via binary search + zero f1/f2 (gemm epilogue atomicAdds).
// ---------------------------------------------------------------------------
__global__ void rowptr_kernel(const int* __restrict__ row,
                              int* __restrict__ row_ptr,
                              float* __restrict__ f1, float* __restrict__ f2) {
  const int i = blockIdx.x * blockDim.x + threadIdx.x;
  if (i > N_NODES) return;
  int lo = 0, hi = E_EDGES;
  while (lo < hi) {
    const int mid = (lo + hi) >> 1;
    if (row[mid] < i) lo = mid + 1; else hi = mid;
  }
  row_ptr[i] = lo;
  if (i < N_NODES) { f1[i] = 0.f; f2[i] = 0.f; }
}

// ---------------------------------------------------------------------------
// Prep B: Wt16[n][k] = bf16(W[k][n])  (transposed, n-major, for B-fragments)
// ---------------------------------------------------------------------------
__global__ void wprep_kernel(const float* __restrict__ W,
                             unsigned short* __restrict__ Wt16) {
  const int n = blockIdx.x;     // 0..127
  const int k = threadIdx.x;    // 0..255
  Wt16[n * IN_F + k] = f32_to_bf16(W[k * OUT_F + n]);
}

// ---------------------------------------------------------------------------
// Kernel 1: Wh16 = bf16(h @ W) via MFMA 16x16x32_bf16.
// Block 128x128 (full OUT_F), BK=32, 256 threads = 4 waves in 2x2 grid,
// each wave a 64x64 quadrant = 4x4 tiles of 16x16. h converted fp32->bf16
// during staging. Fused epilogue: f1/f2 partial dots + shuffle reduce +
// atomicAdd.
// LDS layout: As[128][40] (pad 32->40), Bs[128][40]; epilogue reuses all of
// it as out_stage[128][136] (stride 136 keeps b128 16B-aligned).
// ---------------------------------------------------------------------------
#define AS_STRIDE 40
#define OS_STRIDE 136
__global__ __launch_bounds__(256) void gemm_mfma(
    const float* __restrict__ h, const unsigned short* __restrict__ Wt16,
    const float* __restrict__ a_src, const float* __restrict__ a_dst,
    unsigned short* __restrict__ Wh16, float* __restrict__ f1,
    float* __restrict__ f2) {
  __shared__ unsigned short lds[128 * OS_STRIDE];  // 34816 B
  unsigned short* As = lds;                        // [128][40]
  unsigned short* Bs = lds + 128 * AS_STRIDE;      // [128][40]

  const int tid = threadIdx.x;
  const int lane = tid & 63;
  const int w = tid >> 6;        // wave 0..3
  const int wr = w >> 1;         // wave row 0..1 (x64 rows)
  const int wc = w & 1;          // wave col 0..1 (x64 cols)
  const int quad = lane >> 4;    // 0..3
  const int lm = lane & 15;      // m/n within tile
  const int m0 = blockIdx.x * 128;

  const int srow = tid >> 1;     // staging row 0..127
  const int shalf = tid & 1;     // staging k-half (16 elements)

  f32x4 acc[4][4];
#pragma unroll
  for (int a = 0; a < 4; ++a)
#pragma unroll
    for (int b = 0; b < 4; ++b) acc[a][b] = (f32x4){0.f, 0.f, 0.f, 0.f};

  const int gr = min(m0 + srow, N_NODES - 1);  // clamp tail-block loads

  for (int k0 = 0; k0 < IN_F; k0 += 32) {
    // global loads for this tile
    const float4* hp =
        reinterpret_cast<const float4*>(&h[gr * IN_F + k0 + shalf * 16]);
    const float4 h0 = hp[0], h1 = hp[1], h2 = hp[2], h3 = hp[3];
    const uint4* wp = reinterpret_cast<const uint4*>(
        &Wt16[srow * IN_F + k0 + shalf * 16]);
    const uint4 wv0 = wp[0], wv1 = wp[1];

    __syncthreads();  // previous tile's LDS reads complete
    {
      uint4 p0, p1;
      p0.x = pack_bf16x2(h0.x, h0.y); p0.y = pack_bf16x2(h0.z, h0.w);
      p0.z = pack_bf16x2(h1.x, h1.y); p0.w = pack_bf16x2(h1.z, h1.w);
      p1.x = pack_bf16x2(h2.x, h2.y); p1.y = pack_bf16x2(h2.z, h2.w);
      p1.z = pack_bf16x2(h3.x, h3.y); p1.w = pack_bf16x2(h3.z, h3.w);
      uint4* as = reinterpret_cast<uint4*>(&As[srow * AS_STRIDE + shalf * 16]);
      as[0] = p0; as[1] = p1;
      uint4* bs = reinterpret_cast<uint4*>(&Bs[srow * AS_STRIDE + shalf * 16]);
      bs[0] = wv0; bs[1] = wv1;
    }
    __syncthreads();

    bf16x8 af[4], bf[4];
#pragma unroll
    for (int t = 0; t < 4; ++t) {
      af[t] = *reinterpret_cast<const bf16x8*>(
          &As[(wr * 64 + t * 16 + lm) * AS_STRIDE + quad * 8]);
      bf[t] = *reinterpret_cast<const bf16x8*>(
          &Bs[(wc * 64 + t * 16 + lm) * AS_STRIDE + quad * 8]);
    }
#pragma unroll
    for (int tr = 0; tr < 4; ++tr)
#pragma unroll
      for (int tc = 0; tc < 4; ++tc)
        acc[tr][tc] = __builtin_amdgcn_mfma_f32_16x16x32_bf16(
            af[tr], bf[tc], acc[tr][tc], 0, 0, 0);
  }

  // ---- epilogue 1: fused f1/f2 (rows this lane holds: quad*4+reg per tile)
  float asv[4], adv[4];
#pragma unroll
  for (int tc = 0; tc < 4; ++tc) {
    asv[tc] = a_src[wc * 64 + tc * 16 + lm];
    adv[tc] = a_dst[wc * 64 + tc * 16 + lm];
  }
#pragma unroll
  for (int tr = 0; tr < 4; ++tr) {
#pragma unroll
    for (int reg = 0; reg < 4; ++reg) {
      float p1 = 0.f, p2 = 0.f;
#pragma unroll
      for (int tc = 0; tc < 4; ++tc) {
        p1 = fmaf(acc[tr][tc][reg], asv[tc], p1);
        p2 = fmaf(acc[tr][tc][reg], adv[tc], p2);
      }
#pragma unroll
      for (int o = 1; o < 16; o <<= 1) {  // reduce the 16 lm lanes
        p1 += __shfl_xor(p1, o);
        p2 += __shfl_xor(p2, o);
      }
      const int grow = m0 + wr * 64 + tr * 16 + quad * 4 + reg;
      if (lm == 0 && grow < N_NODES) {
        atomicAdd(&f1[grow], p1);
        atomicAdd(&f2[grow], p2);
      }
    }
  }

  // ---- epilogue 2: stage C tile to LDS (bf16), then coalesced global copy
  __syncthreads();  // done with As/Bs
#pragma unroll
  for (int tr = 0; tr < 4; ++tr)
#pragma unroll
    for (int tc = 0; tc < 4; ++tc)
#pragma unroll
      for (int reg = 0; reg < 4; ++reg)
        lds[(wr * 64 + tr * 16 + quad * 4 + reg) * OS_STRIDE + wc * 64 +
            tc * 16 + lm] = f32_to_bf16(acc[tr][tc][reg]);
  __syncthreads();
  // each (srow, shalf) thread copies 64 contiguous ushorts = 8 uint4
  // (R2 BUG: src stepped 16 ushorts while dst stepped 8 -> half-poisoned Wh)
  if (m0 + srow < N_NODES) {
    uint4* dst =
        reinterpret_cast<uint4*>(&Wh16[(m0 + srow) * OUT_F + shalf * 64]);
    const uint4* src =
        reinterpret_cast<const uint4*>(&lds[srow * OS_STRIDE + shalf * 64]);
#pragma unroll
    for (int i = 0; i < 8; ++i) dst[i] = src[i];
  }
}

// ---------------------------------------------------------------------------
// Kernel 2: segment softmax + SpMM + ELU. ONE WAVE PER NODE.
// Block 256 = 4 waves = 4 nodes. Lane owns features {2*lane, 2*lane+1}.
// Fast path (deg<=128): cache {att,col} per edge in LDS (int2 -> one
// ds_read_b64 broadcast per edge), gather Wh16 as one dword (2x bf16) per
// lane per edge. 1/denom folded into the final scale.
// ---------------------------------------------------------------------------
__global__ __launch_bounds__(256) void gat_v2(
    const unsigned int* __restrict__ Wh16u,  // Wh16 viewed as dwords [N][64]
    const float* __restrict__ f1, const float* __restrict__ f2,
    const int* __restrict__ row_ptr, const int* __restrict__ col,
    float* __restrict__ out) {
  __shared__ int2 edge_s[4][128];

  const int w = threadIdx.x >> 6;
  const int lane = threadIdx.x & 63;
  const int node = blockIdx.x * 4 + w;

  const int start = row_ptr[node];
  const int end = row_ptr[node + 1];
  const int deg = end - start;
  float2* outp = reinterpret_cast<float2*>(&out[node * OUT_F + lane * 2]);

  if (deg == 0) {
    *outp = make_float2(0.f, 0.f);
    return;
  }
  const float f1i = f1[node];
  float acc0 = 0.f, acc1 = 0.f;
  float inv;

  if (deg <= 128) {
    // pass A: logits -> LDS, running max
    float m = -INFINITY;
    for (int idx = lane; idx < deg; idx += 64) {
      const int c = col[start + idx];
      float v = f1i + f2[c];
      v = v > 0.f ? v : LRELU_ALPHA * v;
      edge_s[w][idx] = make_int2(__float_as_int(v), c);
      m = fmaxf(m, v);
    }
#pragma unroll
    for (int o = 32; o > 0; o >>= 1) m = fmaxf(m, __shfl_xor(m, o));
    __builtin_amdgcn_wave_barrier();
    // pass B: exp + sum (store numerator back)
    float s = 0.f;
    for (int idx = lane; idx < deg; idx += 64) {
      const float x = __expf(__int_as_float(edge_s[w][idx].x) - m);
      edge_s[w][idx].x = __float_as_int(x);
      s += x;
    }
#pragma unroll
    for (int o = 32; o > 0; o >>= 1) s += __shfl_xor(s, o);
    inv = 1.f / s;
    __builtin_amdgcn_wave_barrier();
    // pass C: gather + accumulate
    for (int j = 0; j < deg; ++j) {
      const int2 ec = edge_s[w][j];                 // one b64 broadcast
      const float a = __int_as_float(ec.x);
      const unsigned int g = Wh16u[ec.y * 64 + lane];
      acc0 = fmaf(a, __uint_as_float(g << 16), acc0);
      acc1 = fmaf(a, __uint_as_float(g & 0xffff0000u), acc1);
    }
  } else {
    // slow path (deg > 128): 3-pass recompute, no LDS cache
    float m = -INFINITY;
    for (int idx = lane; idx < deg; idx += 64) {
      float v = f1i + f2[col[start + idx]];
      v = v > 0.f ? v : LRELU_ALPHA * v;
      m = fmaxf(m, v);
    }
#pragma unroll
    for (int o = 32; o > 0; o >>= 1) m = fmaxf(m, __shfl_xor(m, o));
    float s = 0.f;
    for (int idx = lane; idx < deg; idx += 64) {
      float v = f1i + f2[col[start + idx]];
      v = v > 0.f ? v : LRELU_ALPHA * v;
      s += __expf(v - m);
    }
#pragma unroll
    for (int o = 32; o > 0; o >>= 1) s += __shfl_xor(s, o);
    inv = 1.f / s;
    for (int j = 0; j < deg; ++j) {
      const int c = col[start + j];
      float v = f1i + f2[c];
      v = v > 0.f ? v : LRELU_ALPHA * v;
      const float a = __expf(v - m);
      const unsigned int g = Wh16u[c * 64 + lane];
      acc0 = fmaf(a, __uint_as_float(g << 16), acc0);
      acc1 = fmaf(a, __uint_as_float(g & 0xffff0000u), acc1);
    }
  }
  acc0 *= inv;
  acc1 *= inv;
  const float o0 = acc0 > 0.f ? acc0 : expm1f(acc0);
  const float o1 = acc1 > 0.f ? acc1 : expm1f(acc1);
  *outp = make_float2(o0, o1);
}

// ---------------------------------------------------------------------------
extern "C" void kernel_launch(void* const* d_in, const int* in_sizes, int n_in,
                              void* d_out, int out_size, void* d_ws,
                              size_t ws_size, hipStream_t stream) {
  const float* h     = (const float*)d_in[0];
  const float* W     = (const float*)d_in[1];
  const float* a_src = (const float*)d_in[2];
  const float* a_dst = (const float*)d_in[3];
  const int*   row   = (const int*)d_in[4];
  const int*   col   = (const int*)d_in[5];
  float* out = (float*)d_out;

  char* ws = (char*)d_ws;
  unsigned short* Wh16 = (unsigned short*)(ws);        // N*128*2 = 25,600,000 B
  float* f1      = (float*)(ws + 25600000);            //    400,000 B
  float* f2      = (float*)(ws + 26000000);            //    400,000 B
  int*   row_ptr = (int*)  (ws + 26400000);            //    400,004 B
  unsigned short* Wt16 = (unsigned short*)(ws + 26800016);  // 64 KB, align16

  hipLaunchKernelGGL(rowptr_kernel, dim3((N_NODES + 256) / 256), dim3(256), 0,
                     stream, row, row_ptr, f1, f2);
  hipLaunchKernelGGL(wprep_kernel, dim3(OUT_F), dim3(IN_F), 0, stream, W, Wt16);
  hipLaunchKernelGGL(gemm_mfma, dim3((N_NODES + 127) / 128), dim3(256), 0,
                     stream, h, Wt16, a_src, a_dst, Wh16, f1, f2);
  hipLaunchKernelGGL(gat_v2, dim3(N_NODES / 4), dim3(256), 0, stream,
                     (const unsigned int*)Wh16, f1, f2, row_ptr, col, out);
}